// Round 2
// baseline (1179.865 us; speedup 1.0000x reference)
//
#include <hip/hip_runtime.h>
#include <hip/hip_bf16.h>
#include <stdint.h>

// Problem dims
#define B_ 4
#define T_ 128
#define H_ 1024
#define N_ 300
#define V_ 50265
#define E_ 4800
#define R_ (B_*T_)   // 512 rows
#define GK 2048

// ---- workspace layout (floats) ----
#define U_OFF     0                       // u_h[1024],u_s[1024],u_x[1024], c at [3072]
#define PS_OFF    3080
#define GG_OFF    3592
#define MG_OFF    4104
#define Z_OFF     4616
#define M_OFF     (Z_OFF + R_*N_)
#define CP_OFF    (M_OFF + R_*N_)
#define GRAPH_OFF (CP_OFF + R_*N_)
#define COV_OFF   (GRAPH_OFF + B_*N_*N_)
#define FLAG_OFF  (COV_OFF + B_*N_)       // int flag: 1=bf16 inputs, 0=f32
#define ABF_OFF   ((FLAG_OFF + 4) & ~3)   // A as bf16 [512][2048] = 524288 floats

// out offsets (elements): total_pro, coverage, pro_switch
#define OUT_COV ((size_t)R_*V_)
#define OUT_PS  (OUT_COV + (size_t)B_*N_)

typedef unsigned short ushort_t;
typedef __bf16 bf16x8 __attribute__((ext_vector_type(8)));
typedef float  f32x4  __attribute__((ext_vector_type(4)));
typedef unsigned short ushort8v __attribute__((ext_vector_type(8)));
typedef unsigned short ushort4v __attribute__((ext_vector_type(4)));
typedef float f32x4v __attribute__((ext_vector_type(4)));

__device__ __forceinline__ ushort_t f2bf(float f) {
    unsigned u = __float_as_uint(f);
    unsigned r = (u + 0x7fffu + ((u >> 16) & 1u)) >> 16;   // RNE
    return (ushort_t)r;
}
template<bool BF> __device__ __forceinline__ float ldv(const void* p, size_t i) {
    if constexpr (BF) {
        unsigned u = ((unsigned)((const ushort_t*)p)[i]) << 16;
        return __uint_as_float(u);
    } else {
        return ((const float*)p)[i];
    }
}
template<bool BF> __device__ __forceinline__ void stv(void* p, size_t i, float v) {
    if constexpr (BF) ((ushort_t*)p)[i] = f2bf(v);
    else              ((float*)p)[i] = v;
}
__device__ __forceinline__ float sigm(float x) { return 1.0f / (1.0f + expf(-x)); }

// async global->LDS, 16B per lane, dest = lds_base + lane*16 (wave-uniform base)
__device__ __forceinline__ void gload_lds16(const ushort_t* g, ushort_t* l) {
    __builtin_amdgcn_global_load_lds(
        (const __attribute__((address_space(1))) unsigned int*)g,
        (__attribute__((address_space(3))) unsigned int*)l, 16, 0, 0);
}

// ---------------------------------------------------------------------------
// Probe: classify input dtype. bf16 N(0,1): every ushort has exponent~[100,140]
// (cnt~256). f32 N(0,1): only hi half-words do (cnt~148). Threshold 200.
// ---------------------------------------------------------------------------
__global__ void k_probe(const ushort_t* __restrict__ x, int* __restrict__ flag)
{
    if (threadIdx.x == 0 && blockIdx.x == 0) {
        int cnt = 0;
        for (int i = 0; i < 256; ++i) {
            const int e = (x[i] >> 7) & 0xff;
            cnt += (e >= 100 && e <= 140) ? 1 : 0;
        }
        *flag = (cnt > 200) ? 1 : 0;
    }
}

// ---------------------------------------------------------------------------
// K_prep: Abf[512][2048] bf16 = concat(hs, qt) along k.  RNE identical to the
// per-tile conversion it replaces (bf16 path is a bit-exact round trip).
// ---------------------------------------------------------------------------
template<bool BF>
__global__ __launch_bounds__(256)
void k_prep(const int* __restrict__ flag, const void* __restrict__ hs,
            const void* __restrict__ qt, ushort_t* __restrict__ Abf)
{
    if (*flag != (BF ? 1 : 0)) return;
    const int g = blockIdx.x * 256 + threadIdx.x;   // 131072 threads, 8 elems each
    const int r  = g >> 8;                          // 256 groups of 8 per row
    const int kc = (g & 255) * 8;
    const void* src = (kc < H_) ? hs : qt;
    const int k = kc & (H_ - 1);
    ushort8v o;
    #pragma unroll
    for (int p = 0; p < 8; ++p) o[p] = f2bf(ldv<BF>(src, (size_t)r*H_ + k + p));
    *(ushort8v*)(Abf + (size_t)r*GK + kc) = o;
}

// ---------------------------------------------------------------------------
// K_u: u rows 0..3071 = (Wh|Ws|Wx) @ Wps; row 3072 -> c = bx.Wps + bps
// ---------------------------------------------------------------------------
template<bool BF>
__global__ __launch_bounds__(256)
void k_u(const int* __restrict__ flag,
         const void* __restrict__ Wh, const void* __restrict__ Wsm,
         const void* __restrict__ Wx, const void* __restrict__ bx,
         const void* __restrict__ Wps, const void* __restrict__ bps,
         float* __restrict__ u)
{
    if (*flag != (BF ? 1 : 0)) return;
    const int t = threadIdx.x, w = t >> 6, l = t & 63;
    const int row = blockIdx.x * 4 + w;
    if (row > 3072) return;
    float s = 0.f;
    if (row < 3072) {
        const void* W = (row < 1024) ? Wh : (row < 2048) ? Wsm : Wx;
        const size_t k = (size_t)(row & 1023);
        for (int h = l; h < H_; h += 64)
            s += ldv<BF>(W, k*H_ + h) * ldv<BF>(Wps, h);
    } else {
        for (int h = l; h < H_; h += 64)
            s += ldv<BF>(bx, h) * ldv<BF>(Wps, h);
    }
    for (int o = 32; o; o >>= 1) s += __shfl_down(s, o);
    if (l == 0) {
        if (row < 3072) u[row] = s;
        else            u[3072] = s + ldv<BF>(bps, 0);
    }
}

// ---------------------------------------------------------------------------
// K_rows: ps/gg/mg per row; writes pro_switch output
// ---------------------------------------------------------------------------
template<bool BF>
__global__ __launch_bounds__(256)
void k_rows(const int* __restrict__ flag,
            const void* __restrict__ hs, const void* __restrict__ qt,
            const void* __restrict__ te, const float* __restrict__ u,
            const void* __restrict__ Wgg, const void* __restrict__ bgg,
            const void* __restrict__ Wmg, const void* __restrict__ bmg,
            float* __restrict__ ps, float* __restrict__ gg, float* __restrict__ mg,
            void* __restrict__ out_ps)
{
    if (*flag != (BF ? 1 : 0)) return;
    const int r = blockIdx.x, t = threadIdx.x;
    const float* uh = u; const float* us = u + 1024; const float* ux = u + 2048;
    float s1 = 0.f, s2 = 0.f, s3 = 0.f;
    for (int k = t; k < H_; k += 256) {
        const float a = ldv<BF>(hs, (size_t)r*H_ + k);
        const float b = ldv<BF>(qt, (size_t)r*H_ + k);
        const float c = ldv<BF>(te, (size_t)r*H_ + k);
        s1 += a*uh[k] + b*us[k] + c*ux[k];
        s2 += a*ldv<BF>(Wgg, k) + b*ldv<BF>(Wgg, H_ + k);
        s3 += a*ldv<BF>(Wmg, k) + b*ldv<BF>(Wmg, H_ + k);
    }
    for (int o = 32; o; o >>= 1) {
        s1 += __shfl_down(s1, o); s2 += __shfl_down(s2, o); s3 += __shfl_down(s3, o);
    }
    __shared__ float red[3][4];
    const int w = t >> 6, l = t & 63;
    if (l == 0) { red[0][w] = s1; red[1][w] = s2; red[2][w] = s3; }
    __syncthreads();
    if (t == 0) {
        const float S1 = red[0][0]+red[0][1]+red[0][2]+red[0][3] + u[3072];
        const float S2 = red[1][0]+red[1][1]+red[1][2]+red[1][3] + ldv<BF>(bgg, 0);
        const float S3 = red[2][0]+red[2][1]+red[2][2]+red[2][3] + ldv<BF>(bmg, 0);
        const float p = sigm(S1);
        ps[r] = p; gg[r] = sigm(S2); mg[r] = sigm(S3);
        stv<BF>(out_ps, r, p);
    }
}

// ---------------------------------------------------------------------------
// k_gbig: total_pro GEMM, BM = 512 (ALL of M), BN = 64, BK = 32, 786 blocks.
// Each B column stripe is read by exactly ONE block (one XCD) -> B read once.
// A: pre-converted bf16 [512][2048], staged via global_load_lds (dwordx4) into
//    double-buffered As with a chunk-XOR swizzle (linear dest + inverse-swz
//    global source + swz read: rule #21) to kill the 8-way ds_read conflict.
// B: f32/bf16 global, 8 scalar loads/thread -> regs -> bf16 LDS [n][k], BKp=40.
// Pipeline: depth-1 prefetch (A->LDS, B->regs) issued before compute(s);
// single __syncthreads per K-step drains vmcnt AFTER the compute phase.
// Wave w computes rows [w*128, w*128+128) x all 64 cols: 8x4 MFMA frags.
// ---------------------------------------------------------------------------
template<bool BF>
__global__ __launch_bounds__(256)
void k_gbig(const int* __restrict__ flag,
            const ushort_t* __restrict__ Abf, const void* __restrict__ Bm,
            const void* __restrict__ bias, const float* __restrict__ ps,
            void* __restrict__ outh)
{
    if (*flag != (BF ? 1 : 0)) return;
    constexpr int BN = 64, BK = 32, BKp = 40, STEPS = GK / BK;  // 64
    __shared__ ushort_t As[2][512 * BK];   // 2 x 32 KB
    __shared__ ushort_t Bs[2][BN * BKp];   // 2 x 5 KB
    const int t = threadIdx.x, w = t >> 6, l = t & 63;
    const int lr = l & 15, lq = l >> 4;
    const int bn0 = blockIdx.x * BN;
    const int wm = w * 128;                 // wave's row base

    // B staging: col nB, k-group kg (8 k each)
    const int nB = t & 63, kg = t >> 6;
    const int gnB = bn0 + nB;
    const size_t gnClamp = (size_t)((gnB < V_) ? gnB : (V_ - 1));
    const bool gnOk = (gnB < V_);

    // A staging (per wave, 8 issues of 1KB): lane row/sub within 16-row group,
    // global chunk pre-swizzled so that LDS chunk x of row m holds global
    // chunk x ^ ((m>>1)&3)  (involution; read applies the same XOR).
    const int aRow = l >> 2;                       // 0..15
    const int aCsrc = (l & 3) ^ ((l >> 3) & 3);    // swizzled source chunk
    const ushort_t* AgBase = Abf + (size_t)wm * GK;

    float bv[8];
    f32x4 acc[8][4] = {};

    auto loadB = [&](int s) {
        const int k0 = s * BK + kg * 8;
        #pragma unroll
        for (int p = 0; p < 8; ++p) {
            const float v = ldv<BF>(Bm, (size_t)(k0 + p) * V_ + gnClamp);
            bv[p] = gnOk ? v : 0.f;
        }
    };
    auto storeB = [&](int buf) {
        ushort8v b0;
        #pragma unroll
        for (int p = 0; p < 8; ++p) b0[p] = f2bf(bv[p]);
        *(ushort8v*)(&Bs[buf][nB * BKp + kg * 8]) = b0;
    };
    auto stageA = [&](int s, int buf) {
        const int k0 = s * BK;
        #pragma unroll
        for (int i = 0; i < 8; ++i) {
            const int m = i * 16 + aRow;                       // row in wave's 128
            const ushort_t* g = AgBase + (size_t)m * GK + k0 + aCsrc * 8;
            ushort_t* lp = &As[buf][(wm + i * 16) * BK];       // wave-uniform base
            gload_lds16(g, lp);
        }
    };
    auto compute = [&](int buf) {
        const int aswz = (lq ^ ((lr >> 1) & 3)) * 8;           // swizzled read chunk
        const ushort_t* a_rd = &As[buf][(wm + lr) * BK + aswz];
        const ushort_t* b_rd = &Bs[buf][lr * BKp + lq * 8];
        bf16x8 bfr[4];
        #pragma unroll
        for (int j = 0; j < 4; ++j) bfr[j] = *(const bf16x8*)(b_rd + j * 16 * BKp);
        #pragma unroll
        for (int i = 0; i < 8; ++i) {
            const bf16x8 af = *(const bf16x8*)(a_rd + i * 16 * BK);
            #pragma unroll
            for (int j = 0; j < 4; ++j)
                acc[i][j] = __builtin_amdgcn_mfma_f32_16x16x32_bf16(af, bfr[j], acc[i][j], 0, 0, 0);
        }
    };

    // prologue
    loadB(0);
    stageA(0, 0);
    storeB(0);            // compiler waits vmcnt for bv
    __syncthreads();      // drains vmcnt(0): As[0] landed; Bs[0] visible
    int cur = 0;
    for (int s = 0; s < STEPS; ++s) {
        const bool more = (s + 1 < STEPS);
        if (more) { loadB(s + 1); stageA(s + 1, cur ^ 1); }
        compute(cur);
        if (more) {
            storeB(cur ^ 1);   // waits bv; gload_lds drains at the barrier
            __syncthreads();
            cur ^= 1;
        }
    }

    // epilogue: out = (acc + bias) * (1 - ps[row])
    #pragma unroll
    for (int j = 0; j < 4; ++j) {
        const int gcol = bn0 + j * 16 + lr;
        if (gcol < V_) {
            const float bvv = ldv<BF>(bias, gcol);
            #pragma unroll
            for (int i = 0; i < 8; ++i) {
                #pragma unroll
                for (int r2 = 0; r2 < 4; ++r2) {
                    const int row = wm + i * 16 + lq * 4 + r2;
                    stv<BF>(outh, (size_t)row * V_ + gcol,
                            (acc[i][j][r2] + bvv) * (1.0f - ps[row]));
                }
            }
        }
    }
}

// ---------------------------------------------------------------------------
// Small MFMA GEMM (copy_pro): unchanged from round 0 (K-split, atomic epilogue)
// ---------------------------------------------------------------------------
template<int GN_, bool BF>
__global__ __launch_bounds__(256)
void k_gemm(const int* __restrict__ flag,
            const void* __restrict__ A1, const void* __restrict__ A2,
            const void* __restrict__ Bm, const void* __restrict__ bias,
            float* __restrict__ outf)
{
    if (*flag != (BF ? 1 : 0)) return;
    constexpr int BM = 128, BN = 128, BK = 32, BKp = 40;
    __shared__ ushort_t As[BM*BK];
    __shared__ ushort_t Bs[BN*BKp];
    const int t = threadIdx.x;
    const int w = t >> 6, l = t & 63;
    const int lr = l & 15, lq = l >> 4;
    const int bn0 = blockIdx.x * BN;
    const int bm0 = blockIdx.y * BM;
    const int wm = (w >> 1) * 64, wn = (w & 1) * 64;

    const int steps = GK/BK/4;
    const int kbeg  = blockIdx.z * steps * BK;

    const int hB = t >> 7;
    const int nB = t & 127;
    const int gnB = bn0 + nB;
    const size_t gnClamp = (size_t)((gnB < GN_) ? gnB : (GN_-1));
    const bool gnOk = (gnB < GN_);

    f32x4 acc[4][4] = {};
    const ushort_t* a_rd = As + (wm + lr)*BK  + lq*8;
    const ushort_t* b_rd = Bs + (wn + lr)*BKp + lq*8;

    ushort8v aBufH[2]; f32x4v aBufF[4]; float bv[16];

    auto load_step = [&](int s) {
        const int k0 = kbeg + s*BK;
        const void* Asrc = (k0 < H_) ? A1 : A2;
        const int kk = k0 & (H_ - 1);
        if constexpr (BF) {
            #pragma unroll
            for (int p = 0; p < 2; ++p) {
                const int slot = p*256 + t, m = slot >> 2, sub = slot & 3;
                aBufH[p] = *(const ushort8v*)((const ushort_t*)Asrc +
                             (size_t)(bm0 + m)*H_ + kk + sub*8);
            }
        } else {
            #pragma unroll
            for (int p = 0; p < 4; ++p) {
                const int slot = p*256 + t, m = slot >> 3, sub = slot & 7;
                aBufF[p] = *(const f32x4v*)((const float*)Asrc +
                             (size_t)(bm0 + m)*H_ + kk + sub*4);
            }
        }
        #pragma unroll
        for (int p = 0; p < 16; ++p) {
            const int k = hB*16 + p;
            const float v = ldv<BF>(Bm, (size_t)(k0 + k)*GN_ + gnClamp);
            bv[p] = gnOk ? v : 0.f;
        }
    };

    auto store_step = [&]() {
        if constexpr (BF) {
            #pragma unroll
            for (int p = 0; p < 2; ++p) {
                const int slot = p*256 + t, m = slot >> 2, sub = slot & 3;
                *(ushort8v*)(As + m*BK + sub*8) = aBufH[p];
            }
        } else {
            #pragma unroll
            for (int p = 0; p < 4; ++p) {
                const int slot = p*256 + t, m = slot >> 3, sub = slot & 7;
                ushort4v h4;
                h4[0] = f2bf(aBufF[p][0]); h4[1] = f2bf(aBufF[p][1]);
                h4[2] = f2bf(aBufF[p][2]); h4[3] = f2bf(aBufF[p][3]);
                *(ushort4v*)(As + m*BK + sub*4) = h4;
            }
        }
        ushort8v b0, b1;
        #pragma unroll
        for (int p = 0; p < 8; ++p)  b0[p] = f2bf(bv[p]);
        #pragma unroll
        for (int p = 0; p < 8; ++p)  b1[p] = f2bf(bv[8+p]);
        *(ushort8v*)(Bs + nB*BKp + hB*16)     = b0;
        *(ushort8v*)(Bs + nB*BKp + hB*16 + 8) = b1;
    };

    load_step(0);
    for (int s = 0; s < steps; ++s) {
        __syncthreads();
        store_step();
        __syncthreads();
        if (s + 1 < steps) load_step(s + 1);

        bf16x8 af[4], bfr[4];
        #pragma unroll
        for (int i = 0; i < 4; ++i) af[i]  = *(const bf16x8*)(a_rd + i*16*BK);
        #pragma unroll
        for (int j = 0; j < 4; ++j) bfr[j] = *(const bf16x8*)(b_rd + j*16*BKp);
        #pragma unroll
        for (int i = 0; i < 4; ++i)
            #pragma unroll
            for (int j = 0; j < 4; ++j)
                acc[i][j] = __builtin_amdgcn_mfma_f32_16x16x32_bf16(af[i], bfr[j], acc[i][j], 0, 0, 0);
    }

    #pragma unroll
    for (int j = 0; j < 4; ++j) {
        const int gcol = bn0 + wn + j*16 + lr;
        if (gcol < GN_) {
            const float bvv = (blockIdx.z == 0) ? ldv<BF>(bias, gcol) : 0.0f;
            #pragma unroll
            for (int i = 0; i < 4; ++i)
                #pragma unroll
                for (int r2 = 0; r2 < 4; ++r2) {
                    const int row = bm0 + wm + i*16 + lq*4 + r2;
                    atomicAdd(outf + (size_t)row*GN_ + gcol, acc[i][j][r2] + bvv);
                }
        }
    }
}

// ---------------------------------------------------------------------------
__global__ void k_graph(const int* __restrict__ edges, float* __restrict__ Graph)
{
    const int gid = blockIdx.x * 256 + threadIdx.x;
    if (gid >= B_*E_) return;
    const int b = gid / E_, e = gid - b*E_;
    const int* eb = edges + (size_t)b * 2 * E_;
    const int i = eb[e], j = eb[E_ + e];
    atomicAdd(Graph + (size_t)b*N_*N_ + (size_t)j*N_ + i, 1.0f);   // Graph^T
}

__global__ void k_scan(const float* __restrict__ cp, const float* __restrict__ mg,
                       float* __restrict__ M)
{
    const int gid = blockIdx.x * 256 + threadIdx.x;
    if (gid >= B_*N_) return;
    const int b = gid / N_, n = gid - b*N_;
    float m = 0.f;
    for (int tt = 0; tt < T_; ++tt) {
        const int r = b*T_ + tt;
        const float g = mg[r];
        m = cp[(size_t)r*N_ + n]*g + m*(1.f - g);
        M[(size_t)r*N_ + n] = m;
    }
}

__global__ __launch_bounds__(320)
void k_gsem(const float* __restrict__ Graph, const float* __restrict__ M,
            const float* __restrict__ cp, const float* __restrict__ gg,
            const float* __restrict__ ps, float* __restrict__ z,
            float* __restrict__ cov)
{
    const int r = blockIdx.x;
    const int b = r >> 7;
    const int t = threadIdx.x, w = t >> 6, l = t & 63;
    __shared__ float ml[N_];
    __shared__ float red[5];
    if (t < N_) ml[t] = M[(size_t)r*N_ + t];
    __syncthreads();
    float g = 0.f;
    if (t < N_) {
        const float* GT = Graph + (size_t)b*N_*N_ + t;
        #pragma unroll 4
        for (int j = 0; j < N_; ++j) g += GT[j*N_] * ml[j];
    }
    float zv = 0.f;
    if (t < N_) {
        const float ggv = gg[r];
        const float pg = cp[(size_t)r*N_ + t]*ggv + g*(1.f - ggv);
        zv = pg * ps[r];
        z[(size_t)r*N_ + t] = zv;
    }
    float mv = (t < N_) ? zv : -3.0e38f;
    for (int o = 32; o; o >>= 1) mv = fmaxf(mv, __shfl_down(mv, o));
    if (l == 0) red[w] = mv;
    __syncthreads();
    const float bmx = fmaxf(fmaxf(fmaxf(red[0], red[1]), fmaxf(red[2], red[3])), red[4]);
    __syncthreads();
    const float e = (t < N_) ? expf(zv - bmx) : 0.f;
    float sv = e;
    for (int o = 32; o; o >>= 1) sv += __shfl_down(sv, o);
    if (l == 0) red[w] = sv;
    __syncthreads();
    const float tot = red[0] + red[1] + red[2] + red[3] + red[4];
    if (t < N_) atomicAdd(cov + b*N_ + t, e / tot);
}

template<bool BF>
__global__ void k_cov(const int* __restrict__ flag,
                      const float* __restrict__ cov, void* __restrict__ out)
{
    if (*flag != (BF ? 1 : 0)) return;
    const int gid = blockIdx.x * 256 + threadIdx.x;
    if (gid < B_*N_) stv<BF>(out, gid, cov[gid]);
}

// out[r, idx[n]] += sum of duplicates' z (first-occurrence thread owns column)
template<bool BF>
__global__ __launch_bounds__(256)
void k_fixup(const int* __restrict__ flag, const int* __restrict__ nidx,
             const float* __restrict__ z, void* __restrict__ out)
{
    if (*flag != (BF ? 1 : 0)) return;
    __shared__ int li[N_];
    const int t = threadIdx.x;
    for (int i = t; i < N_; i += 256) li[i] = nidx[i];
    __syncthreads();
    const int gid = blockIdx.x * 256 + t;
    if (gid >= R_*N_) return;
    const int r = gid / N_, n = gid - r*N_;
    const int v = li[n];
    for (int j = 0; j < n; ++j) if (li[j] == v) return;
    float s = z[(size_t)r*N_ + n];
    for (int j = n + 1; j < N_; ++j) if (li[j] == v) s += z[(size_t)r*N_ + j];
    const size_t o = (size_t)r*V_ + v;
    stv<BF>(out, o, ldv<BF>(out, o) + s);
}

// ---------------------------------------------------------------------------
extern "C" void kernel_launch(void* const* d_in, const int* in_sizes, int n_in,
                              void* d_out, int out_size, void* d_ws, size_t ws_size,
                              hipStream_t stream)
{
    (void)in_sizes; (void)n_in; (void)out_size; (void)ws_size;
    const void* hs  = d_in[0];
    const void* qt  = d_in[1];
    const void* te  = d_in[2];
    const int*  edg = (const int*)d_in[3];
    const int*  nid = (const int*)d_in[4];
    const void* Wg  = d_in[5];
    const void* bg  = d_in[6];
    const void* Wh  = d_in[7];
    const void* Wsm = d_in[8];
    const void* Wx  = d_in[9];
    const void* bx  = d_in[10];
    const void* Wps = d_in[11];
    const void* bps = d_in[12];
    const void* Wc  = d_in[13];
    const void* bc  = d_in[14];
    const void* Wgg = d_in[15];
    const void* bgg = d_in[16];
    const void* Wmg = d_in[17];
    const void* bmg = d_in[18];
    float* ws = (float*)d_ws;
    int* flag = (int*)(ws + FLAG_OFF);
    ushort_t* Abf = (ushort_t*)(ws + ABF_OFF);

    k_probe<<<1, 64, 0, stream>>>((const ushort_t*)hs, flag);
    hipMemsetAsync(ws + CP_OFF, 0,
                   (size_t)(R_*N_ + B_*N_*N_ + B_*N_) * sizeof(float), stream);

    k_prep<true ><<<512, 256, 0, stream>>>(flag, hs, qt, Abf);
    k_prep<false><<<512, 256, 0, stream>>>(flag, hs, qt, Abf);
    k_u<true ><<<769, 256, 0, stream>>>(flag, Wh, Wsm, Wx, bx, Wps, bps, ws + U_OFF);
    k_u<false><<<769, 256, 0, stream>>>(flag, Wh, Wsm, Wx, bx, Wps, bps, ws + U_OFF);
    k_rows<true ><<<R_, 256, 0, stream>>>(flag, hs, qt, te, ws + U_OFF, Wgg, bgg, Wmg, bmg,
                                          ws + PS_OFF, ws + GG_OFF, ws + MG_OFF,
                                          (ushort_t*)d_out + OUT_PS);
    k_rows<false><<<R_, 256, 0, stream>>>(flag, hs, qt, te, ws + U_OFF, Wgg, bgg, Wmg, bmg,
                                          ws + PS_OFF, ws + GG_OFF, ws + MG_OFF,
                                          (float*)d_out + OUT_PS);
    {   // copy_pro = concat(qt,te) @ Wc + bc  (K-split x4, f32 atomic epilogue)
        dim3 g((N_ + 127) / 128, 4, 4);
        k_gemm<N_, true ><<<g, 256, 0, stream>>>(flag, qt, te, Wc, bc, ws + CP_OFF);
        k_gemm<N_, false><<<g, 256, 0, stream>>>(flag, qt, te, Wc, bc, ws + CP_OFF);
    }
    k_graph<<<(B_*E_ + 255)/256, 256, 0, stream>>>(edg, ws + GRAPH_OFF);
    k_scan<<<(B_*N_ + 255)/256, 256, 0, stream>>>(ws + CP_OFF, ws + MG_OFF, ws + M_OFF);
    k_gsem<<<R_, 320, 0, stream>>>(ws + GRAPH_OFF, ws + M_OFF, ws + CP_OFF,
                                   ws + GG_OFF, ws + PS_OFF, ws + Z_OFF, ws + COV_OFF);
    k_cov<true ><<<(B_*N_ + 255)/256, 256, 0, stream>>>(flag, ws + COV_OFF,
                                                        (ushort_t*)d_out + OUT_COV);
    k_cov<false><<<(B_*N_ + 255)/256, 256, 0, stream>>>(flag, ws + COV_OFF,
                                                        (float*)d_out + OUT_COV);
    {   // total_pro = (hq @ Wg + bg) * (1 - ps):  786 N-stripe blocks, full M
        k_gbig<true ><<<(V_ + 63)/64, 256, 0, stream>>>(flag, Abf, Wg, bg,
                                                        ws + PS_OFF, d_out);
        k_gbig<false><<<(V_ + 63)/64, 256, 0, stream>>>(flag, Abf, Wg, bg,
                                                        ws + PS_OFF, d_out);
    }
    k_fixup<true ><<<(R_*N_ + 255)/256, 256, 0, stream>>>(flag, nid, ws + Z_OFF, d_out);
    k_fixup<false><<<(R_*N_ + 255)/256, 256, 0, stream>>>(flag, nid, ws + Z_OFF, d_out);
}

// Round 3
// 1017.110 us; speedup vs baseline: 1.1600x; 1.1600x over previous
//
#include <hip/hip_runtime.h>
#include <hip/hip_bf16.h>
#include <stdint.h>

// Problem dims
#define B_ 4
#define T_ 128
#define H_ 1024
#define N_ 300
#define V_ 50265
#define E_ 4800
#define R_ (B_*T_)   // 512 rows
#define GK 2048

// ---- workspace layout (floats) ----
#define U_OFF     0                       // u_h[1024],u_s[1024],u_x[1024], c at [3072]
#define PS_OFF    3080
#define GG_OFF    3592
#define MG_OFF    4104
#define Z_OFF     4616
#define M_OFF     (Z_OFF + R_*N_)
#define CP_OFF    (M_OFF + R_*N_)
#define GRAPH_OFF (CP_OFF + R_*N_)
#define COV_OFF   (GRAPH_OFF + B_*N_*N_)
#define FLAG_OFF  (COV_OFF + B_*N_)       // int flag: 1=bf16 inputs, 0=f32
#define ABF_OFF   ((FLAG_OFF + 4) & ~3)   // A as bf16 [512][2048] (2 MB)

// out offsets (elements): total_pro, coverage, pro_switch
#define OUT_COV ((size_t)R_*V_)
#define OUT_PS  (OUT_COV + (size_t)B_*N_)

typedef unsigned short ushort_t;
typedef __bf16 bf16x8 __attribute__((ext_vector_type(8)));
typedef float  f32x4  __attribute__((ext_vector_type(4)));
typedef unsigned short ushort8v __attribute__((ext_vector_type(8)));
typedef unsigned short ushort4v __attribute__((ext_vector_type(4)));
typedef float f32x4v __attribute__((ext_vector_type(4)));

__device__ __forceinline__ ushort_t f2bf(float f) {
    unsigned u = __float_as_uint(f);
    unsigned r = (u + 0x7fffu + ((u >> 16) & 1u)) >> 16;   // RNE
    return (ushort_t)r;
}
template<bool BF> __device__ __forceinline__ float ldv(const void* p, size_t i) {
    if constexpr (BF) {
        unsigned u = ((unsigned)((const ushort_t*)p)[i]) << 16;
        return __uint_as_float(u);
    } else {
        return ((const float*)p)[i];
    }
}
template<bool BF> __device__ __forceinline__ void stv(void* p, size_t i, float v) {
    if constexpr (BF) ((ushort_t*)p)[i] = f2bf(v);
    else              ((float*)p)[i] = v;
}
__device__ __forceinline__ float sigm(float x) { return 1.0f / (1.0f + expf(-x)); }

// ---------------------------------------------------------------------------
// Probe: classify input dtype. bf16 N(0,1): every ushort has exponent~[100,140]
// (cnt~256). f32 N(0,1): only hi half-words do (cnt~148). Threshold 200.
// ---------------------------------------------------------------------------
__global__ void k_probe(const ushort_t* __restrict__ x, int* __restrict__ flag)
{
    if (threadIdx.x == 0 && blockIdx.x == 0) {
        int cnt = 0;
        for (int i = 0; i < 256; ++i) {
            const int e = (x[i] >> 7) & 0xff;
            cnt += (e >= 100 && e <= 140) ? 1 : 0;
        }
        *flag = (cnt > 200) ? 1 : 0;
    }
}

// ---------------------------------------------------------------------------
// K_prep: Abf[512][2048] bf16 = concat(hs, qt) along k.  RNE identical to the
// per-tile conversion it replaces (bf16 path is a bit-exact round trip).
// ---------------------------------------------------------------------------
template<bool BF>
__global__ __launch_bounds__(256)
void k_prep(const int* __restrict__ flag, const void* __restrict__ hs,
            const void* __restrict__ qt, ushort_t* __restrict__ Abf)
{
    if (*flag != (BF ? 1 : 0)) return;
    const int g = blockIdx.x * 256 + threadIdx.x;   // 131072 threads, 8 elems each
    const int r  = g >> 8;                          // 256 groups of 8 per row
    const int kc = (g & 255) * 8;
    const void* src = (kc < H_) ? hs : qt;
    const int k = kc & (H_ - 1);
    ushort8v o;
    #pragma unroll
    for (int p = 0; p < 8; ++p) o[p] = f2bf(ldv<BF>(src, (size_t)r*H_ + k + p));
    *(ushort8v*)(Abf + (size_t)r*GK + kc) = o;
}

// ---------------------------------------------------------------------------
// K_u: u rows 0..3071 = (Wh|Ws|Wx) @ Wps; row 3072 -> c = bx.Wps + bps
// ---------------------------------------------------------------------------
template<bool BF>
__global__ __launch_bounds__(256)
void k_u(const int* __restrict__ flag,
         const void* __restrict__ Wh, const void* __restrict__ Wsm,
         const void* __restrict__ Wx, const void* __restrict__ bx,
         const void* __restrict__ Wps, const void* __restrict__ bps,
         float* __restrict__ u)
{
    if (*flag != (BF ? 1 : 0)) return;
    const int t = threadIdx.x, w = t >> 6, l = t & 63;
    const int row = blockIdx.x * 4 + w;
    if (row > 3072) return;
    float s = 0.f;
    if (row < 3072) {
        const void* W = (row < 1024) ? Wh : (row < 2048) ? Wsm : Wx;
        const size_t k = (size_t)(row & 1023);
        for (int h = l; h < H_; h += 64)
            s += ldv<BF>(W, k*H_ + h) * ldv<BF>(Wps, h);
    } else {
        for (int h = l; h < H_; h += 64)
            s += ldv<BF>(bx, h) * ldv<BF>(Wps, h);
    }
    for (int o = 32; o; o >>= 1) s += __shfl_down(s, o);
    if (l == 0) {
        if (row < 3072) u[row] = s;
        else            u[3072] = s + ldv<BF>(bps, 0);
    }
}

// ---------------------------------------------------------------------------
// K_rows: ps/gg/mg per row; writes pro_switch output
// ---------------------------------------------------------------------------
template<bool BF>
__global__ __launch_bounds__(256)
void k_rows(const int* __restrict__ flag,
            const void* __restrict__ hs, const void* __restrict__ qt,
            const void* __restrict__ te, const float* __restrict__ u,
            const void* __restrict__ Wgg, const void* __restrict__ bgg,
            const void* __restrict__ Wmg, const void* __restrict__ bmg,
            float* __restrict__ ps, float* __restrict__ gg, float* __restrict__ mg,
            void* __restrict__ out_ps)
{
    if (*flag != (BF ? 1 : 0)) return;
    const int r = blockIdx.x, t = threadIdx.x;
    const float* uh = u; const float* us = u + 1024; const float* ux = u + 2048;
    float s1 = 0.f, s2 = 0.f, s3 = 0.f;
    for (int k = t; k < H_; k += 256) {
        const float a = ldv<BF>(hs, (size_t)r*H_ + k);
        const float b = ldv<BF>(qt, (size_t)r*H_ + k);
        const float c = ldv<BF>(te, (size_t)r*H_ + k);
        s1 += a*uh[k] + b*us[k] + c*ux[k];
        s2 += a*ldv<BF>(Wgg, k) + b*ldv<BF>(Wgg, H_ + k);
        s3 += a*ldv<BF>(Wmg, k) + b*ldv<BF>(Wmg, H_ + k);
    }
    for (int o = 32; o; o >>= 1) {
        s1 += __shfl_down(s1, o); s2 += __shfl_down(s2, o); s3 += __shfl_down(s3, o);
    }
    __shared__ float red[3][4];
    const int w = t >> 6, l = t & 63;
    if (l == 0) { red[0][w] = s1; red[1][w] = s2; red[2][w] = s3; }
    __syncthreads();
    if (t == 0) {
        const float S1 = red[0][0]+red[0][1]+red[0][2]+red[0][3] + u[3072];
        const float S2 = red[1][0]+red[1][1]+red[1][2]+red[1][3] + ldv<BF>(bgg, 0);
        const float S3 = red[2][0]+red[2][1]+red[2][2]+red[2][3] + ldv<BF>(bmg, 0);
        const float p = sigm(S1);
        ps[r] = p; gg[r] = sigm(S2); mg[r] = sigm(S3);
        stv<BF>(out_ps, r, p);
    }
}

// ---------------------------------------------------------------------------
// k_gv: total_pro GEMM. BM=128, BN=128, BK=32, full K per block.
// Grid 1600 with XCD co-location swizzle: blockIdx%8 = XCD (round-robin
// dispatch), so mapping mb=q&3, jn=(q>>2)*8+xcd puts the 4 M-blocks of each
// N-stripe on consecutive slots of ONE XCD -> B stripe L2-shared (3/4 hits).
// A from pre-converted bf16 Abf (2x16B loads/thread). B: 16 scalar loads.
// Double-buffered LDS, ONE barrier per K-step; prefetch regs for s+2 issued
// after the barrier, consumed at store(s+2) a full compute phase later ->
// barrier has no outstanding VMEM to drain.
// ---------------------------------------------------------------------------
template<bool BF>
__global__ __launch_bounds__(256)
void k_gv(const int* __restrict__ flag, const ushort_t* __restrict__ Abf,
          const void* __restrict__ Bm, const void* __restrict__ bias,
          const float* __restrict__ ps, void* __restrict__ outh)
{
    if (*flag != (BF ? 1 : 0)) return;
    constexpr int BM = 128, BN = 128, BK = 32, BKp = 40, STEPS = GK / BK;
    constexpr int NSTRIPE = (V_ + BN - 1) / BN;   // 393
    const int id = blockIdx.x;
    const int xcd = id & 7, q = id >> 3;
    const int mb = q & 3;
    const int jn = (q >> 2) * 8 + xcd;
    if (jn >= NSTRIPE) return;
    const int bm0 = mb * BM, bn0 = jn * BN;

    __shared__ ushort_t As[2][BM * BK];   // 2 x 8 KB
    __shared__ ushort_t Bs[2][BN * BKp];  // 2 x 10 KB
    const int t = threadIdx.x, w = t >> 6, l = t & 63;
    const int lr = l & 15, lq = l >> 4;
    const int wm = (w >> 1) * 64, wn = (w & 1) * 64;

    const int hB = t >> 7, nB = t & 127;
    const int gnB = bn0 + nB;
    const size_t gnClamp = (size_t)((gnB < V_) ? gnB : (V_ - 1));
    const bool gnOk = (gnB < V_);

    f32x4 acc[4][4] = {};
    ushort8v aR[2]; float bv[16];

    auto load_step = [&](int s) {
        const int k0 = s * BK;
        #pragma unroll
        for (int p = 0; p < 2; ++p) {
            const int slot = p*256 + t, m = slot >> 2, sub = slot & 3;
            aR[p] = *(const ushort8v*)(Abf + (size_t)(bm0 + m)*GK + k0 + sub*8);
        }
        #pragma unroll
        for (int p = 0; p < 16; ++p) {
            const float v = ldv<BF>(Bm, (size_t)(k0 + hB*16 + p)*V_ + gnClamp);
            bv[p] = gnOk ? v : 0.f;
        }
    };
    auto store_step = [&](int buf) {
        #pragma unroll
        for (int p = 0; p < 2; ++p) {
            const int slot = p*256 + t, m = slot >> 2, sub = slot & 3;
            *(ushort8v*)(&As[buf][m*BK + sub*8]) = aR[p];
        }
        ushort8v b0, b1;
        #pragma unroll
        for (int p = 0; p < 8; ++p) b0[p] = f2bf(bv[p]);
        #pragma unroll
        for (int p = 0; p < 8; ++p) b1[p] = f2bf(bv[8+p]);
        *(ushort8v*)(&Bs[buf][nB*BKp + hB*16])     = b0;
        *(ushort8v*)(&Bs[buf][nB*BKp + hB*16 + 8]) = b1;
    };
    auto compute = [&](int buf) {
        const ushort_t* a_rd = &As[buf][(wm + lr)*BK  + lq*8];
        const ushort_t* b_rd = &Bs[buf][(wn + lr)*BKp + lq*8];
        bf16x8 af[4], bfr[4];
        #pragma unroll
        for (int i = 0; i < 4; ++i) af[i]  = *(const bf16x8*)(a_rd + i*16*BK);
        #pragma unroll
        for (int j = 0; j < 4; ++j) bfr[j] = *(const bf16x8*)(b_rd + j*16*BKp);
        #pragma unroll
        for (int i = 0; i < 4; ++i)
            #pragma unroll
            for (int j = 0; j < 4; ++j)
                acc[i][j] = __builtin_amdgcn_mfma_f32_16x16x32_bf16(af[i], bfr[j], acc[i][j], 0, 0, 0);
    };

    // prologue
    load_step(0);
    store_step(0);        // waits on load(0) regs
    __syncthreads();      // tile 0 visible; nothing else outstanding
    load_step(1);         // in flight under compute(0)
    for (int s = 0; s < STEPS; ++s) {
        compute(s & 1);
        if (s + 1 < STEPS) {
            store_step((s + 1) & 1);   // waits load(s+1) (issued 1 compute ago)
            __syncthreads();           // publish tile s+1; no VMEM outstanding
            if (s + 2 < STEPS) load_step(s + 2);
        }
    }

    // epilogue: out = (acc + bias) * (1 - ps[row])  (C/D: col=lane&15, row=(lane>>4)*4+reg)
    float omp[16];
    #pragma unroll
    for (int i = 0; i < 4; ++i)
        #pragma unroll
        for (int r2 = 0; r2 < 4; ++r2)
            omp[i*4 + r2] = 1.0f - ps[bm0 + wm + i*16 + lq*4 + r2];
    #pragma unroll
    for (int j = 0; j < 4; ++j) {
        const int gcol = bn0 + wn + j*16 + lr;
        if (gcol < V_) {
            const float bvv = ldv<BF>(bias, gcol);
            #pragma unroll
            for (int i = 0; i < 4; ++i)
                #pragma unroll
                for (int r2 = 0; r2 < 4; ++r2) {
                    const int row = bm0 + wm + i*16 + lq*4 + r2;
                    stv<BF>(outh, (size_t)row*V_ + gcol,
                            (acc[i][j][r2] + bvv) * omp[i*4 + r2]);
                }
        }
    }
}

// ---------------------------------------------------------------------------
// Small MFMA GEMM (copy_pro): K-split x4, f32 atomic epilogue (round-0 proven)
// ---------------------------------------------------------------------------
template<int GN_, bool BF>
__global__ __launch_bounds__(256)
void k_gemm(const int* __restrict__ flag,
            const void* __restrict__ A1, const void* __restrict__ A2,
            const void* __restrict__ Bm, const void* __restrict__ bias,
            float* __restrict__ outf)
{
    if (*flag != (BF ? 1 : 0)) return;
    constexpr int BM = 128, BN = 128, BK = 32, BKp = 40;
    __shared__ ushort_t As[BM*BK];
    __shared__ ushort_t Bs[BN*BKp];
    const int t = threadIdx.x;
    const int w = t >> 6, l = t & 63;
    const int lr = l & 15, lq = l >> 4;
    const int bn0 = blockIdx.x * BN;
    const int bm0 = blockIdx.y * BM;
    const int wm = (w >> 1) * 64, wn = (w & 1) * 64;

    const int steps = GK/BK/4;
    const int kbeg  = blockIdx.z * steps * BK;

    const int hB = t >> 7;
    const int nB = t & 127;
    const int gnB = bn0 + nB;
    const size_t gnClamp = (size_t)((gnB < GN_) ? gnB : (GN_-1));
    const bool gnOk = (gnB < GN_);

    f32x4 acc[4][4] = {};
    const ushort_t* a_rd = As + (wm + lr)*BK  + lq*8;
    const ushort_t* b_rd = Bs + (wn + lr)*BKp + lq*8;

    ushort8v aBufH[2]; f32x4v aBufF[4]; float bv[16];

    auto load_step = [&](int s) {
        const int k0 = kbeg + s*BK;
        const void* Asrc = (k0 < H_) ? A1 : A2;
        const int kk = k0 & (H_ - 1);
        if constexpr (BF) {
            #pragma unroll
            for (int p = 0; p < 2; ++p) {
                const int slot = p*256 + t, m = slot >> 2, sub = slot & 3;
                aBufH[p] = *(const ushort8v*)((const ushort_t*)Asrc +
                             (size_t)(bm0 + m)*H_ + kk + sub*8);
            }
        } else {
            #pragma unroll
            for (int p = 0; p < 4; ++p) {
                const int slot = p*256 + t, m = slot >> 3, sub = slot & 7;
                aBufF[p] = *(const f32x4v*)((const float*)Asrc +
                             (size_t)(bm0 + m)*H_ + kk + sub*4);
            }
        }
        #pragma unroll
        for (int p = 0; p < 16; ++p) {
            const int k = hB*16 + p;
            const float v = ldv<BF>(Bm, (size_t)(k0 + k)*GN_ + gnClamp);
            bv[p] = gnOk ? v : 0.f;
        }
    };

    auto store_step = [&]() {
        if constexpr (BF) {
            #pragma unroll
            for (int p = 0; p < 2; ++p) {
                const int slot = p*256 + t, m = slot >> 2, sub = slot & 3;
                *(ushort8v*)(As + m*BK + sub*8) = aBufH[p];
            }
        } else {
            #pragma unroll
            for (int p = 0; p < 4; ++p) {
                const int slot = p*256 + t, m = slot >> 3, sub = slot & 7;
                ushort4v h4;
                h4[0] = f2bf(aBufF[p][0]); h4[1] = f2bf(aBufF[p][1]);
                h4[2] = f2bf(aBufF[p][2]); h4[3] = f2bf(aBufF[p][3]);
                *(ushort4v*)(As + m*BK + sub*4) = h4;
            }
        }
        ushort8v b0, b1;
        #pragma unroll
        for (int p = 0; p < 8; ++p)  b0[p] = f2bf(bv[p]);
        #pragma unroll
        for (int p = 0; p < 8; ++p)  b1[p] = f2bf(bv[8+p]);
        *(ushort8v*)(Bs + nB*BKp + hB*16)     = b0;
        *(ushort8v*)(Bs + nB*BKp + hB*16 + 8) = b1;
    };

    load_step(0);
    for (int s = 0; s < steps; ++s) {
        __syncthreads();
        store_step();
        __syncthreads();
        if (s + 1 < steps) load_step(s + 1);

        bf16x8 af[4], bfr[4];
        #pragma unroll
        for (int i = 0; i < 4; ++i) af[i]  = *(const bf16x8*)(a_rd + i*16*BK);
        #pragma unroll
        for (int j = 0; j < 4; ++j) bfr[j] = *(const bf16x8*)(b_rd + j*16*BKp);
        #pragma unroll
        for (int i = 0; i < 4; ++i)
            #pragma unroll
            for (int j = 0; j < 4; ++j)
                acc[i][j] = __builtin_amdgcn_mfma_f32_16x16x32_bf16(af[i], bfr[j], acc[i][j], 0, 0, 0);
    }

    #pragma unroll
    for (int j = 0; j < 4; ++j) {
        const int gcol = bn0 + wn + j*16 + lr;
        if (gcol < GN_) {
            const float bvv = (blockIdx.z == 0) ? ldv<BF>(bias, gcol) : 0.0f;
            #pragma unroll
            for (int i = 0; i < 4; ++i)
                #pragma unroll
                for (int r2 = 0; r2 < 4; ++r2) {
                    const int row = bm0 + wm + i*16 + lq*4 + r2;
                    atomicAdd(outf + (size_t)row*GN_ + gcol, acc[i][j][r2] + bvv);
                }
        }
    }
}

// ---------------------------------------------------------------------------
__global__ void k_graph(const int* __restrict__ edges, float* __restrict__ Graph)
{
    const int gid = blockIdx.x * 256 + threadIdx.x;
    if (gid >= B_*E_) return;
    const int b = gid / E_, e = gid - b*E_;
    const int* eb = edges + (size_t)b * 2 * E_;
    const int i = eb[e], j = eb[E_ + e];
    atomicAdd(Graph + (size_t)b*N_*N_ + (size_t)j*N_ + i, 1.0f);   // Graph^T
}

__global__ void k_scan(const float* __restrict__ cp, const float* __restrict__ mg,
                       float* __restrict__ M)
{
    const int gid = blockIdx.x * 256 + threadIdx.x;
    if (gid >= B_*N_) return;
    const int b = gid / N_, n = gid - b*N_;
    float m = 0.f;
    for (int tt = 0; tt < T_; ++tt) {
        const int r = b*T_ + tt;
        const float g = mg[r];
        m = cp[(size_t)r*N_ + n]*g + m*(1.f - g);
        M[(size_t)r*N_ + n] = m;
    }
}

__global__ __launch_bounds__(320)
void k_gsem(const float* __restrict__ Graph, const float* __restrict__ M,
            const float* __restrict__ cp, const float* __restrict__ gg,
            const float* __restrict__ ps, float* __restrict__ z,
            float* __restrict__ cov)
{
    const int r = blockIdx.x;
    const int b = r >> 7;
    const int t = threadIdx.x, w = t >> 6, l = t & 63;
    __shared__ float ml[N_];
    __shared__ float red[5];
    if (t < N_) ml[t] = M[(size_t)r*N_ + t];
    __syncthreads();
    float g = 0.f;
    if (t < N_) {
        const float* GT = Graph + (size_t)b*N_*N_ + t;
        #pragma unroll 4
        for (int j = 0; j < N_; ++j) g += GT[j*N_] * ml[j];
    }
    float zv = 0.f;
    if (t < N_) {
        const float ggv = gg[r];
        const float pg = cp[(size_t)r*N_ + t]*ggv + g*(1.f - ggv);
        zv = pg * ps[r];
        z[(size_t)r*N_ + t] = zv;
    }
    float mv = (t < N_) ? zv : -3.0e38f;
    for (int o = 32; o; o >>= 1) mv = fmaxf(mv, __shfl_down(mv, o));
    if (l == 0) red[w] = mv;
    __syncthreads();
    const float bmx = fmaxf(fmaxf(fmaxf(red[0], red[1]), fmaxf(red[2], red[3])), red[4]);
    __syncthreads();
    const float e = (t < N_) ? expf(zv - bmx) : 0.f;
    float sv = e;
    for (int o = 32; o; o >>= 1) sv += __shfl_down(sv, o);
    if (l == 0) red[w] = sv;
    __syncthreads();
    const float tot = red[0] + red[1] + red[2] + red[3] + red[4];
    if (t < N_) atomicAdd(cov + b*N_ + t, e / tot);
}

template<bool BF>
__global__ void k_cov(const int* __restrict__ flag,
                      const float* __restrict__ cov, void* __restrict__ out)
{
    if (*flag != (BF ? 1 : 0)) return;
    const int gid = blockIdx.x * 256 + threadIdx.x;
    if (gid < B_*N_) stv<BF>(out, gid, cov[gid]);
}

// out[r, idx[n]] += sum of duplicates' z (first-occurrence thread owns column)
template<bool BF>
__global__ __launch_bounds__(256)
void k_fixup(const int* __restrict__ flag, const int* __restrict__ nidx,
             const float* __restrict__ z, void* __restrict__ out)
{
    if (*flag != (BF ? 1 : 0)) return;
    __shared__ int li[N_];
    const int t = threadIdx.x;
    for (int i = t; i < N_; i += 256) li[i] = nidx[i];
    __syncthreads();
    const int gid = blockIdx.x * 256 + t;
    if (gid >= R_*N_) return;
    const int r = gid / N_, n = gid - r*N_;
    const int v = li[n];
    for (int j = 0; j < n; ++j) if (li[j] == v) return;
    float s = z[(size_t)r*N_ + n];
    for (int j = n + 1; j < N_; ++j) if (li[j] == v) s += z[(size_t)r*N_ + j];
    const size_t o = (size_t)r*V_ + v;
    stv<BF>(out, o, ldv<BF>(out, o) + s);
}

// ---------------------------------------------------------------------------
extern "C" void kernel_launch(void* const* d_in, const int* in_sizes, int n_in,
                              void* d_out, int out_size, void* d_ws, size_t ws_size,
                              hipStream_t stream)
{
    (void)in_sizes; (void)n_in; (void)out_size; (void)ws_size;
    const void* hs  = d_in[0];
    const void* qt  = d_in[1];
    const void* te  = d_in[2];
    const int*  edg = (const int*)d_in[3];
    const int*  nid = (const int*)d_in[4];
    const void* Wg  = d_in[5];
    const void* bg  = d_in[6];
    const void* Wh  = d_in[7];
    const void* Wsm = d_in[8];
    const void* Wx  = d_in[9];
    const void* bx  = d_in[10];
    const void* Wps = d_in[11];
    const void* bps = d_in[12];
    const void* Wc  = d_in[13];
    const void* bc  = d_in[14];
    const void* Wgg = d_in[15];
    const void* bgg = d_in[16];
    const void* Wmg = d_in[17];
    const void* bmg = d_in[18];
    float* ws = (float*)d_ws;
    int* flag = (int*)(ws + FLAG_OFF);
    ushort_t* Abf = (ushort_t*)(ws + ABF_OFF);

    k_probe<<<1, 64, 0, stream>>>((const ushort_t*)hs, flag);
    hipMemsetAsync(ws + CP_OFF, 0,
                   (size_t)(R_*N_ + B_*N_*N_ + B_*N_) * sizeof(float), stream);

    k_prep<true ><<<512, 256, 0, stream>>>(flag, hs, qt, Abf);
    k_prep<false><<<512, 256, 0, stream>>>(flag, hs, qt, Abf);
    k_u<true ><<<769, 256, 0, stream>>>(flag, Wh, Wsm, Wx, bx, Wps, bps, ws + U_OFF);
    k_u<false><<<769, 256, 0, stream>>>(flag, Wh, Wsm, Wx, bx, Wps, bps, ws + U_OFF);
    k_rows<true ><<<R_, 256, 0, stream>>>(flag, hs, qt, te, ws + U_OFF, Wgg, bgg, Wmg, bmg,
                                          ws + PS_OFF, ws + GG_OFF, ws + MG_OFF,
                                          (ushort_t*)d_out + OUT_PS);
    k_rows<false><<<R_, 256, 0, stream>>>(flag, hs, qt, te, ws + U_OFF, Wgg, bgg, Wmg, bmg,
                                          ws + PS_OFF, ws + GG_OFF, ws + MG_OFF,
                                          (float*)d_out + OUT_PS);
    {   // copy_pro = concat(qt,te) @ Wc + bc  (K-split x4, f32 atomic epilogue)
        dim3 g((N_ + 127) / 128, 4, 4);
        k_gemm<N_, true ><<<g, 256, 0, stream>>>(flag, qt, te, Wc, bc, ws + CP_OFF);
        k_gemm<N_, false><<<g, 256, 0, stream>>>(flag, qt, te, Wc, bc, ws + CP_OFF);
    }
    k_graph<<<(B_*E_ + 255)/256, 256, 0, stream>>>(edg, ws + GRAPH_OFF);
    k_scan<<<(B_*N_ + 255)/256, 256, 0, stream>>>(ws + CP_OFF, ws + MG_OFF, ws + M_OFF);
    k_gsem<<<R_, 320, 0, stream>>>(ws + GRAPH_OFF, ws + M_OFF, ws + CP_OFF,
                                   ws + GG_OFF, ws + PS_OFF, ws + Z_OFF, ws + COV_OFF);
    k_cov<true ><<<(B_*N_ + 255)/256, 256, 0, stream>>>(flag, ws + COV_OFF,
                                                        (ushort_t*)d_out + OUT_COV);
    k_cov<false><<<(B_*N_ + 255)/256, 256, 0, stream>>>(flag, ws + COV_OFF,
                                                        (float*)d_out + OUT_COV);
    {   // total_pro = (hq @ Wg + bg) * (1 - ps): XCD co-located (4M x 393N)
        k_gv<true ><<<1600, 256, 0, stream>>>(flag, Abf, Wg, bg, ws + PS_OFF, d_out);
        k_gv<false><<<1600, 256, 0, stream>>>(flag, Abf, Wg, bg, ws + PS_OFF, d_out);
    }
    k_fixup<true ><<<(R_*N_ + 255)/256, 256, 0, stream>>>(flag, nid, ws + Z_OFF, d_out);
    k_fixup<false><<<(R_*N_ + 255)/256, 256, 0, stream>>>(flag, nid, ws + Z_OFF, d_out);
}